// Round 15
// baseline (2754.149 us; speedup 1.0000x reference)
//
#include <hip/hip_runtime.h>

#define N_ITEMS 20000
#define N_USERS 2048
#define NNZ     4000000
#define LDP     2112   // padded XT leading dim (breaks L2/L3 set aliasing)
#define QITEMS  5000   // items per quarter-phase
#define CAP_Q   128    // per-(row,quarter) bucket; Poisson(50), P(>128) ~ 1e-18

typedef float    f32x4 __attribute__((ext_vector_type(4)));
typedef float    f32x2 __attribute__((ext_vector_type(2)));
typedef unsigned u32x4 __attribute__((ext_vector_type(4)));
typedef unsigned u32x2 __attribute__((ext_vector_type(2)));

// ---------------- ws layout (bytes) ----------------
#define OFF_XT     ((size_t)0)                    // bf16 [20000][2112] = 84,480,000
#define OFF_CSRPK  ((size_t)84480000)             // u32 [80000][128] = 40,960,000
#define OFF_CNT    (OFF_CSRPK + 40960000)         // int [80000] = 320,000
// total ~125.8 MB

static __device__ __forceinline__ unsigned short f2bf(float f) {
  unsigned u = __float_as_uint(f);
  unsigned r = (u + 0x7fffu + ((u >> 16) & 1u)) >> 16;
  return (unsigned short)r;
}

// X [N_USERS][N_ITEMS] f32  ->  XT [N_ITEMS][LDP] bf16 (padded)
__global__ __launch_bounds__(256) void transpose_kernel(
    const float* __restrict__ X, unsigned short* __restrict__ XT) {
  __shared__ float tile[64][65];
  int k0 = blockIdx.x * 64;
  int u0 = blockIdx.y * 64;
  int lane = threadIdx.x & 63;
  int dq = threadIdx.x >> 6;
  #pragma unroll
  for (int m = 0; m < 16; ++m) {
    int u = u0 + dq + 4 * m;
    int k = k0 + lane;
    float v = 0.f;
    if (k < N_ITEMS) v = X[(size_t)u * N_ITEMS + k];
    tile[lane][dq + 4 * m] = v;
  }
  __syncthreads();
  #pragma unroll
  for (int m = 0; m < 16; ++m) {
    int k = k0 + dq + 4 * m;
    if (k < N_ITEMS)
      XT[(size_t)k * LDP + u0 + lane] = f2bf(tile[dq + 4 * m][lane]);
  }
}

// COO -> (row, quarter) buckets, 1 nnz/thread (max parallelism for the
// atomic+random-store latency chain). entry = (col_local<<16) | bf16(val).
__global__ __launch_bounds__(256) void scatter_kernel(
    const int* __restrict__ rows, const int* __restrict__ cols,
    const float* __restrict__ vals, int* __restrict__ cnt,
    unsigned* __restrict__ csr_pk) {
  int i = blockIdx.x * 256 + threadIdx.x;  // grid exactly NNZ/256
  int r = rows[i];
  int c = cols[i];
  float v = vals[i];
  int q = c / QITEMS;              // 0..3 (compiler: magic-mul)
  int cl = c - q * QITEMS;         // < 5000
  int bin = (r << 2) + q;
  int pos = atomicAdd(&cnt[bin], 1);
  if (pos >= CAP_Q) pos = CAP_Q - 1;  // astronomically unlikely
  csr_pk[(bin << 7) + pos] = ((unsigned)cl << 16) | (unsigned)f2bf(v);
}

// Phase-locked SpMM: one quarter q per dispatch (stream order = barrier).
// Per dispatch, XCD x gathers ONLY from (users 256x..256x+255, quarter q)
// = 256 x 5000 x 2B = 2.56 MB < 4 MB L2 -> pinned, no drift.
// dwordx2 gather covers 4 users/lane -> ONE gather instr per entry serves
// all 256 users of the XCD (32M total wave-gathers, half of R12).
// WG: 256 thr = 4 waves; 8 rows x 256 users; grid 2500 rb x 8 xcd.
// Partials accumulate across phases through out via NT load/add/store.
__global__ __launch_bounds__(256) void spmm_kernel(
    const int* __restrict__ cnt, const unsigned* __restrict__ csr_pk,
    const unsigned short* __restrict__ xt, float* __restrict__ out, int q) {
  __shared__ float tile[8][260];
  int wg = blockIdx.x;
  int xcd = wg & 7;
  int rb = wg >> 3;              // [0, 2500)
  int u0 = xcd * 256;
  int r0 = rb * 8;
  int lane = threadIdx.x & 63;
  int wave = __builtin_amdgcn_readfirstlane((int)(threadIdx.x >> 6));
  unsigned lane8 = 8 * (unsigned)lane;
  const char* xtb = (const char*)(xt + u0) + (size_t)q * QITEMS * (LDP * 2);

#define LOAD8(E, BASE)                                                       \
  { u32x4 q0 = __builtin_nontemporal_load(                                   \
        reinterpret_cast<const u32x4*>(csr_pk + (BASE)));                    \
    u32x4 q1 = __builtin_nontemporal_load(                                   \
        reinterpret_cast<const u32x4*>(csr_pk + (BASE) + 4));                \
    E[0] = q0.x; E[1] = q0.y; E[2] = q0.z; E[3] = q0.w;                      \
    E[4] = q1.x; E[5] = q1.y; E[6] = q1.z; E[7] = q1.w; }
#define GATHER8(G, E)                                                        \
  { _Pragma("unroll")                                                        \
    for (int k = 0; k < 8; ++k)                                              \
      G[k] = *reinterpret_cast<const u32x2*>(                                \
          xtb + ((E[k] >> 16) * (unsigned)(LDP * 2) + lane8)); }
#define FMA8(G, E)                                                           \
  { _Pragma("unroll")                                                        \
    for (int k = 0; k < 8; ++k) {                                            \
      float vv = __uint_as_float(E[k] << 16);       /* exact bf16 */         \
      f32x2 v2; v2.x = vv; v2.y = vv;                                        \
      f32x2 x01, x23;                                                        \
      x01.x = __uint_as_float(G[k].x << 16);                                 \
      x01.y = __uint_as_float(G[k].x);              /* lo bits = noise */    \
      x23.x = __uint_as_float(G[k].y << 16);                                 \
      x23.y = __uint_as_float(G[k].y);              /* lo bits = noise */    \
      a01 = __builtin_elementwise_fma(v2, x01, a01);                         \
      a23 = __builtin_elementwise_fma(v2, x23, a23);                         \
    } }

  #pragma unroll 1
  for (int rr = 0; rr < 2; ++rr) {
    int r = r0 + wave * 2 + rr;
    int bin = (r << 2) + q;
    int jb = bin << 7;
    int cr = __builtin_amdgcn_readfirstlane(cnt[bin]);
    if (cr > CAP_Q) cr = CAP_Q;
    int nb = (cr + 7) >> 3;  // zero-padded buckets: all batches full
    f32x2 a01, a23;
    a01.x = 0.f; a01.y = 0.f; a23.x = 0.f; a23.y = 0.f;
    if (nb >= 2) {
      unsigned e0[8], e1[8];
      u32x2 g0[8], g1[8];
      LOAD8(e0, jb)
      GATHER8(g0, e0)
      LOAD8(e1, jb + 8)
      int b = 0;
      for (; b + 3 < nb; b += 2) {
        GATHER8(g1, e1)              // issue gathers b+1
        FMA8(g0, e0)                 // compute b
        LOAD8(e0, jb + (b + 2) * 8)
        GATHER8(g0, e0)              // issue gathers b+2
        FMA8(g1, e1)                 // compute b+1
        LOAD8(e1, jb + (b + 3) * 8)
      }
      GATHER8(g1, e1)
      FMA8(g0, e0)
      if (nb - b == 3) {
        LOAD8(e0, jb + (b + 2) * 8)
        GATHER8(g0, e0)
        FMA8(g1, e1)
        FMA8(g0, e0)
      } else {
        FMA8(g1, e1)
      }
    } else if (nb == 1) {
      unsigned e0[8];
      u32x2 g0[8];
      LOAD8(e0, jb)
      GATHER8(g0, e0)
      FMA8(g0, e0)
    }
    f32x4 o;
    o.x = a01.x; o.y = a01.y; o.z = a23.x; o.w = a23.y;
    *reinterpret_cast<f32x4*>(&tile[wave * 2 + rr][4 * lane]) = o;
  }
#undef LOAD8
#undef GATHER8
#undef FMA8

  __syncthreads();
  // epilogue: thread t = user u0+t; rows r0..r0+7 = 32B, 2x f32x4.
  int t = threadIdx.x;
  float* op = out + (size_t)(u0 + t) * N_ITEMS + r0;
  f32x4 o0, o1;
  o0.x = tile[0][t]; o0.y = tile[1][t]; o0.z = tile[2][t]; o0.w = tile[3][t];
  o1.x = tile[4][t]; o1.y = tile[5][t]; o1.z = tile[6][t]; o1.w = tile[7][t];
  if (q) {  // accumulate partials from previous phases (NT: bypass L2)
    f32x4 i0 = __builtin_nontemporal_load(reinterpret_cast<const f32x4*>(op));
    f32x4 i1 = __builtin_nontemporal_load(reinterpret_cast<const f32x4*>(op) + 1);
    o0 += i0;
    o1 += i1;
  }
  __builtin_nontemporal_store(o0, reinterpret_cast<f32x4*>(op));
  __builtin_nontemporal_store(o1, reinterpret_cast<f32x4*>(op) + 1);
}

extern "C" void kernel_launch(void* const* d_in, const int* in_sizes, int n_in,
                              void* d_out, int out_size, void* d_ws, size_t ws_size,
                              hipStream_t stream) {
  const float* X      = (const float*)d_in[0];
  const float* S_vals = (const float*)d_in[1];
  const int*   S_rows = (const int*)d_in[2];
  const int*   S_cols = (const int*)d_in[3];
  float* out = (float*)d_out;

  char* ws = (char*)d_ws;
  unsigned short* XT = (unsigned short*)(ws + OFF_XT);
  unsigned* csr_pk   = (unsigned*)(ws + OFF_CSRPK);
  int* cnt           = (int*)(ws + OFF_CNT);

  hipMemsetAsync(cnt, 0, 4 * N_ITEMS * sizeof(int), stream);
  hipMemsetAsync(csr_pk, 0, (size_t)4 * N_ITEMS * CAP_Q * sizeof(unsigned), stream);
  transpose_kernel<<<dim3(313, 32), 256, 0, stream>>>(X, XT);
  scatter_kernel<<<NNZ / 256, 256, 0, stream>>>(S_rows, S_cols, S_vals, cnt, csr_pk);
  // 4 quarter-phase dispatches; stream serialization = global barrier.
  for (int q = 0; q < 4; ++q)
    spmm_kernel<<<2500 * 8, 256, 0, stream>>>(cnt, csr_pk, XT, out, q);
}

// Round 16
// 1039.922 us; speedup vs baseline: 2.6484x; 2.6484x over previous
//
#include <hip/hip_runtime.h>

#define N_ITEMS 20000
#define N_USERS 2048
#define NNZ     4000000
#define LDP     2112   // padded XT leading dim (breaks L2/L3 set aliasing)
#define HALF_ITEMS 10000
#define CAP_H   192    // per-(row,half) bucket; Poisson(100), P(>192) ~ 1e-16

typedef float    f32x4 __attribute__((ext_vector_type(4)));
typedef unsigned u32x4 __attribute__((ext_vector_type(4)));

// ---------------- ws layout (bytes) ----------------
#define OFF_XT     ((size_t)0)                    // bf16 [20000][2112] = 84,480,000
#define OFF_CSRPK  ((size_t)84480000)             // u32 [40000][192] = 30,720,000
#define OFF_CNT    (OFF_CSRPK + 30720000)         // int [40000]

static __device__ __forceinline__ unsigned short f2bf(float f) {
  unsigned u = __float_as_uint(f);
  unsigned r = (u + 0x7fffu + ((u >> 16) & 1u)) >> 16;
  return (unsigned short)r;
}

// X [N_USERS][N_ITEMS] f32  ->  XT [N_ITEMS][LDP] bf16 (padded)
__global__ __launch_bounds__(256) void transpose_kernel(
    const float* __restrict__ X, unsigned short* __restrict__ XT) {
  __shared__ float tile[64][65];
  int k0 = blockIdx.x * 64;
  int u0 = blockIdx.y * 64;
  int lane = threadIdx.x & 63;
  int dq = threadIdx.x >> 6;
  #pragma unroll
  for (int m = 0; m < 16; ++m) {
    int u = u0 + dq + 4 * m;
    int k = k0 + lane;
    float v = 0.f;
    if (k < N_ITEMS) v = X[(size_t)u * N_ITEMS + k];
    tile[lane][dq + 4 * m] = v;
  }
  __syncthreads();
  #pragma unroll
  for (int m = 0; m < 16; ++m) {
    int k = k0 + dq + 4 * m;
    if (k < N_ITEMS)
      XT[(size_t)k * LDP + u0 + lane] = f2bf(tile[dq + 4 * m][lane]);
  }
}

// COO -> (row, col-half) buckets, 1 nnz/thread.
// entry = (col_local << 16) | bf16(val), col_local < 10000.
__global__ __launch_bounds__(256) void scatter_kernel(
    const int* __restrict__ rows, const int* __restrict__ cols,
    const float* __restrict__ vals, int* __restrict__ cnt,
    unsigned* __restrict__ csr_pk) {
  int i = blockIdx.x * 256 + threadIdx.x;  // grid exactly NNZ/256
  int r = rows[i];
  int c = cols[i];
  float v = vals[i];
  int h = (c >= HALF_ITEMS) ? 1 : 0;
  int bin = 2 * r + h;
  int pos = atomicAdd(&cnt[bin], 1);
  if (pos >= CAP_H) pos = CAP_H - 1;  // astronomically unlikely
  csr_pk[bin * CAP_H + pos] =
      ((unsigned)(c - h * HALF_ITEMS) << 16) | (unsigned)f2bf(v);
}

// Phase-locked SpMM: ONE (uc, h) phase per dispatch; stream order between
// the 4 dispatches is the global barrier. Within a dispatch, every WG on
// XCD x gathers ONLY from slice (uchunk 2x+uc, half h) = 128u x 10000 x 2B
// = 2.56 MB < 4 MB L2 -> pinned working set, no drift (proven in R14).
// WG: 256 thr = 4 waves; 8 rows x 128 users; grid 2500 rb x 8 xcd.
// 3-deep gather pipeline (proven in R12): with pinned slices, gather
// latency is L2-class (~200-300cy) and 24 in-flight gathers/wave cover it.
// h0: partial tile -> out (NT). h1: NT-load partials, accumulate, store.
__global__ __launch_bounds__(256) void spmm_kernel(
    const int* __restrict__ cnt, const unsigned* __restrict__ csr_pk,
    const unsigned short* __restrict__ xt, float* __restrict__ out,
    int uc, int h) {
  __shared__ float tile[8][132];
  int wg = blockIdx.x;
  int xcd = wg & 7;
  int rb = wg >> 3;              // [0, 2500)
  int u0 = (xcd * 2 + uc) * 128;
  int r0 = rb * 8;
  int lane = threadIdx.x & 63;
  int wave = __builtin_amdgcn_readfirstlane((int)(threadIdx.x >> 6));
  unsigned lane4 = 4 * (unsigned)lane;
  const char* xtb = (const char*)(xt + (size_t)h * HALF_ITEMS * LDP + u0);
  int ul = threadIdx.x >> 1;          // user-local [0,128)
  int rhalf = (threadIdx.x & 1) * 4;  // row sub-block {0,4}
  float* op = out + (size_t)(u0 + ul) * N_ITEMS + r0 + rhalf;

#define LOAD8(E, BASE)                                                       \
  { u32x4 q0 = __builtin_nontemporal_load(                                   \
        reinterpret_cast<const u32x4*>(csr_pk + (BASE)));                    \
    u32x4 q1 = __builtin_nontemporal_load(                                   \
        reinterpret_cast<const u32x4*>(csr_pk + (BASE) + 4));                \
    E[0] = q0.x; E[1] = q0.y; E[2] = q0.z; E[3] = q0.w;                      \
    E[4] = q1.x; E[5] = q1.y; E[6] = q1.z; E[7] = q1.w; }
#define GATHER8(G, E)                                                        \
  { _Pragma("unroll")                                                        \
    for (int k = 0; k < 8; ++k)                                              \
      G[k] = *reinterpret_cast<const unsigned*>(                             \
          xtb + ((E[k] >> 16) * (unsigned)(LDP * 2) + lane4)); }
#define FMA8(G, E)                                                           \
  { _Pragma("unroll")                                                        \
    for (int k = 0; k < 8; ++k) {                                            \
      float v  = __uint_as_float(E[k] << 16);     /* exact bf16 */           \
      float xl = __uint_as_float(G[k] << 16);                                \
      float xh = __uint_as_float(G[k]);           /* lo bits = noise */      \
      if (k & 1) { a2 = fmaf(v, xl, a2); a3 = fmaf(v, xh, a3); }             \
      else       { a0 = fmaf(v, xl, a0); a1 = fmaf(v, xh, a1); }             \
    } }

  if (h) {  // stage h0 partials: coalesced NT loads -> LDS in acc layout
    f32x4 i0 = __builtin_nontemporal_load(reinterpret_cast<const f32x4*>(op));
    tile[rhalf + 0][ul] = i0.x; tile[rhalf + 1][ul] = i0.y;
    tile[rhalf + 2][ul] = i0.z; tile[rhalf + 3][ul] = i0.w;
    __syncthreads();
  }

  #pragma unroll 1
  for (int rr = 0; rr < 2; ++rr) {
    int r = r0 + wave * 2 + rr;
    int bin = 2 * r + h;
    int jb = bin * CAP_H;
    int cr = __builtin_amdgcn_readfirstlane(cnt[bin]);
    if (cr > CAP_H) cr = CAP_H;
    int nb = (cr + 7) >> 3;  // zero-padded buckets: all batches full
    float a0 = 0.f, a1 = 0.f, a2 = 0.f, a3 = 0.f;
    if (h) {  // own row's staged partials (written only at iteration end)
      a0 = tile[wave * 2 + rr][2 * lane];
      a1 = tile[wave * 2 + rr][2 * lane + 1];
    }
    if (nb >= 3) {
      unsigned e0[8], e1[8], e2[8], g0[8], g1[8], g2[8];
      LOAD8(e0, jb)
      GATHER8(g0, e0)
      LOAD8(e1, jb + 8)
      GATHER8(g1, e1)
      LOAD8(e2, jb + 16)
      int b = 0;
      // invariant: g0=g(b), g1=g(b+1) issued; e2=entries(b+2) loaded
      for (; b + 5 < nb; b += 3) {
        GATHER8(g2, e2)              // issue b+2
        FMA8(g0, e0)                 // consume b
        LOAD8(e0, jb + (b + 3) * 8)
        GATHER8(g0, e0)              // issue b+3
        FMA8(g1, e1)                 // consume b+1
        LOAD8(e1, jb + (b + 4) * 8)
        GATHER8(g1, e1)              // issue b+4
        FMA8(g2, e2)                 // consume b+2
        LOAD8(e2, jb + (b + 5) * 8)
      }
      int m = nb - b;  // 3, 4, or 5
      GATHER8(g2, e2)
      FMA8(g0, e0)
      if (m == 3) {
        FMA8(g1, e1)
        FMA8(g2, e2)
      } else if (m == 4) {
        LOAD8(e0, jb + (b + 3) * 8)
        GATHER8(g0, e0)
        FMA8(g1, e1)
        FMA8(g2, e2)
        FMA8(g0, e0)
      } else {
        LOAD8(e0, jb + (b + 3) * 8)
        GATHER8(g0, e0)
        FMA8(g1, e1)
        LOAD8(e1, jb + (b + 4) * 8)
        GATHER8(g1, e1)
        FMA8(g2, e2)
        FMA8(g0, e0)
        FMA8(g1, e1)
      }
    } else if (nb == 2) {
      unsigned e0[8], e1[8], g0[8], g1[8];
      LOAD8(e0, jb)
      GATHER8(g0, e0)
      LOAD8(e1, jb + 8)
      GATHER8(g1, e1)
      FMA8(g0, e0)
      FMA8(g1, e1)
    } else if (nb == 1) {
      unsigned e0[8], g0[8];
      LOAD8(e0, jb)
      GATHER8(g0, e0)
      FMA8(g0, e0)
    }
    tile[wave * 2 + rr][2 * lane]     = a0 + a2;
    tile[wave * 2 + rr][2 * lane + 1] = a1 + a3;
  }
#undef LOAD8
#undef GATHER8
#undef FMA8

  __syncthreads();
  f32x4 o;
  o.x = tile[rhalf + 0][ul]; o.y = tile[rhalf + 1][ul];
  o.z = tile[rhalf + 2][ul]; o.w = tile[rhalf + 3][ul];
  __builtin_nontemporal_store(o, reinterpret_cast<f32x4*>(op));
}

extern "C" void kernel_launch(void* const* d_in, const int* in_sizes, int n_in,
                              void* d_out, int out_size, void* d_ws, size_t ws_size,
                              hipStream_t stream) {
  const float* X      = (const float*)d_in[0];
  const float* S_vals = (const float*)d_in[1];
  const int*   S_rows = (const int*)d_in[2];
  const int*   S_cols = (const int*)d_in[3];
  float* out = (float*)d_out;

  char* ws = (char*)d_ws;
  unsigned short* XT = (unsigned short*)(ws + OFF_XT);
  unsigned* csr_pk   = (unsigned*)(ws + OFF_CSRPK);
  int* cnt           = (int*)(ws + OFF_CNT);

  hipMemsetAsync(cnt, 0, 2 * N_ITEMS * sizeof(int), stream);
  hipMemsetAsync(csr_pk, 0, (size_t)2 * N_ITEMS * CAP_H * sizeof(unsigned), stream);
  transpose_kernel<<<dim3(313, 32), 256, 0, stream>>>(X, XT);
  scatter_kernel<<<NNZ / 256, 256, 0, stream>>>(S_rows, S_cols, S_vals, cnt, csr_pk);
  // 4 phase dispatches; stream serialization = global barrier between phases.
  for (int p = 0; p < 4; ++p)
    spmm_kernel<<<2500 * 8, 256, 0, stream>>>(cnt, csr_pk, XT, out,
                                              p >> 1, p & 1);
}